// Round 1
// baseline (251.522 us; speedup 1.0000x reference)
//
#include <hip/hip_runtime.h>

// contract(off): numpy-emulating fp32 ops (esq, rescue zsq/dist) must round mul
// and add separately. Explicit fmaf/fma and MFMA are unaffected.
#pragma clang fp contract(off)

#define K_CODES 512
#define D_DIM 256
#define NPIX 65536
#define TAU 3e-4f
#define STRA 264   // A LDS row stride in shorts: 528 B, 16B-aligned
// z layout [B=64, D=256, H*W=1024]; pixel n = b*1024 + hw.

typedef __attribute__((ext_vector_type(8))) short bf16x8;
typedef __attribute__((ext_vector_type(4))) float f32x4;

// B fragments pre-packed in wave-lane order (validated r8): index
// ((kc*32 + nb)*64 + lane)*8 holds B[n = nb*16 + (lane&15)][k = kc*32 + (lane>>4)*8 + j].
__device__ unsigned short g_bph[8 * 32 * 64 * 8];  // hi
__device__ unsigned short g_bpl[8 * 32 * 64 * 8];  // lo
__device__ float4 g_cbF4[(D_DIM / 4) * K_CODES];   // fp32 cb for rescue (exact)
__device__ float  g_esq[K_CODES];                  // numpy-pairwise fp32 ||e_k||^2
__device__ int    g_list[NPIX];
__device__ int    g_count;

static __device__ __forceinline__ unsigned short f2bf(float x) {
    unsigned u = __float_as_uint(x);
    return (unsigned short)((u + 0x7FFFu + ((u >> 16) & 1u)) >> 16);   // RNE
}
static __device__ __forceinline__ float bf2f(unsigned short h) {
    return __uint_as_float((unsigned)h << 16);
}

// 64 blocks x 256: thread = (k, kc, quad). 4x the CU parallelism of the r10
// 16-block version; numerics byte-identical (same f2bf, same esq pairwise
// order, same cbF4 values).
__global__ __launch_bounds__(256) void prep_cb(const float* __restrict__ cb) {
    if (blockIdx.x == 0 && threadIdx.x == 0) g_count = 0;
    const int gt   = blockIdx.x * 256 + threadIdx.x;   // 0..16383
    const int k    = gt >> 5;                          // 0..511
    const int sub  = gt & 31;
    const int kc   = sub >> 2;                         // 0..7
    const int quad = sub & 3;                          // 0..3
    const float* row = cb + k * D_DIM;
    const int nb = k >> 4, nl = k & 15;
    const int lane = quad * 16 + nl;

    unsigned short h8[8], l8[8];
    #pragma unroll
    for (int j = 0; j < 8; ++j) {
        float x = row[kc * 32 + quad * 8 + j];
        h8[j] = f2bf(x);
        l8[j] = f2bf(x - bf2f(h8[j]));   // x-hi exact (Sterbenz)
    }
    const int dst = ((kc * 32 + nb) * 64 + lane) * 8;
    *(uint4*)&g_bph[dst] = *(uint4*)&h8[0];
    *(uint4*)&g_bpl[dst] = *(uint4*)&l8[0];

    // cbF4 scatter distributed: each (k,sub) covers dq = 2*sub, 2*sub+1.
    #pragma unroll
    for (int u = 0; u < 2; ++u) {
        const int dq = sub * 2 + u;
        g_cbF4[dq * K_CODES + k] = make_float4(row[4*dq], row[4*dq+1], row[4*dq+2], row[4*dq+3]);
    }

    if (sub == 0) {
        // e_sq = np.sum(row*row): pairwise n=256 -> p(0:128)+p(128:256); 8 accums each.
        float s[2];
        for (int blk = 0; blk < 2; ++blk) {
            const float* a = row + blk * 128;
            float r[8];
            #pragma unroll
            for (int j = 0; j < 8; ++j) { float x = a[j]; r[j] = x * x; }
            for (int i = 8; i < 128; i += 8)
                #pragma unroll
                for (int j = 0; j < 8; ++j) { float x = a[i + j]; r[j] += x * x; }
            s[blk] = ((r[0] + r[1]) + (r[2] + r[3])) + ((r[4] + r[5]) + (r[6] + r[7]));
        }
        g_esq[k] = s[0] + s[1];
    }
}

// Two-pass-tj restructure of the validated r8/r10 kernel: each wave processes
// its 64 codes as two sequential 32-code halves (acc[4][2] = 32 regs instead
// of 64). Per output element the MFMA chain sees identical inputs in the
// identical K-order -> acc values bit-identical to r10. The freed registers
// fund: B-prefetch 4-deep (covers L2 latency ~200-300 cy), A-prefetch 2-deep
// (covers LDS latency), full 24-step unroll (no bcur movs, immediate LDS
// offsets), setprio around the MFMA cluster. Target <=128 VGPR (2 blocks/CU).
__global__ __launch_bounds__(512, 4) void pass1_fused(const float* __restrict__ z,
                                                      int* __restrict__ out) {
    __shared__ unsigned short Az[2][64 * STRA];   // [0]=hi, [1]=lo ; [px][d]
    __shared__ float sP_mn[16][64];               // partition (w*2+h) min
    __shared__ int   sP_ic[16][64];               // idx | (cnt<<16)

    const int lane = threadIdx.x & 63;
    const int w    = __builtin_amdgcn_readfirstlane((int)(threadIdx.x >> 6));
    const int l16  = lane & 15, quad = lane >> 4;
    const int n0   = (int)blockIdx.x * 64;        // 64 | 1024 -> same b

    // ---- Prologue: stage A (validated r8). wave w: d-chunk [w*32,w*32+32), lane = px.
    {
        const float* zb = z + ((size_t)(n0 >> 10) << 18) + (n0 & 1023);
        const int px = lane, dc = w;
        #pragma unroll
        for (int half = 0; half < 2; ++half) {
            float x[16];
            #pragma unroll
            for (int j = 0; j < 16; ++j)
                x[j] = zb[(size_t)(dc * 32 + half * 16 + j) * 1024 + px]; // coalesced
            unsigned short hh[16], ll[16];
            #pragma unroll
            for (int j = 0; j < 16; ++j) {
                hh[j] = f2bf(x[j]);
                ll[j] = f2bf(x[j] - bf2f(hh[j]));
            }
            const int o = px * STRA + dc * 32 + half * 16;
            *(uint4*)&Az[0][o]     = *(uint4*)&hh[0];
            *(uint4*)&Az[0][o + 8] = *(uint4*)&hh[8];
            *(uint4*)&Az[1][o]     = *(uint4*)&ll[0];
            *(uint4*)&Az[1][o + 8] = *(uint4*)&ll[8];
        }
    }
    __syncthreads();

    for (int h = 0; h < 2; ++h) {
        const int nb0 = w * 4 + h * 2;

        f32x4 acc[4][2];
        #pragma unroll
        for (int i = 0; i < 4; ++i)
            #pragma unroll
            for (int j = 0; j < 2; ++j)
                acc[i][j] = (f32x4){0.f, 0.f, 0.f, 0.f};

        bf16x8 bq[4][2];   // B ring, 4 steps deep (L2-hot global)
        bf16x8 aq[2][4];   // A ring, 2 steps deep (LDS)

        // step st: seg = st>>3 (0: zh*ch, 1: zh*cl, 2: zl*ch), kc = st&7.
        auto bload = [&](int slot, int st) {
            const int seg = st >> 3, kc = st & 7;
            const unsigned short* bp = (seg == 1) ? g_bpl : g_bph;
            #pragma unroll
            for (int tj = 0; tj < 2; ++tj)   // 512 B coalesced per wave
                bq[slot][tj] = *(const bf16x8*)&bp[((kc * 32 + nb0 + tj) * 64 + lane) * 8];
        };
        auto aload = [&](int slot, int st) {
            const int seg = st >> 3, kc = st & 7;
            const unsigned short* As = (seg == 2) ? &Az[1][0] : &Az[0][0];
            #pragma unroll
            for (int ti = 0; ti < 4; ++ti)   // imm-offset ds_read_b128 x4
                aq[slot][ti] = *(const bf16x8*)&As[(ti * 16 + l16) * STRA + kc * 32 + quad * 8];
        };

        bload(0, 0); bload(1, 1); bload(2, 2); bload(3, 3);
        aload(0, 0); aload(1, 1);

        #pragma unroll
        for (int st = 0; st < 24; ++st) {
            __builtin_amdgcn_s_setprio(1);
            #pragma unroll
            for (int ti = 0; ti < 4; ++ti)
                #pragma unroll
                for (int tj = 0; tj < 2; ++tj)
                    acc[ti][tj] = __builtin_amdgcn_mfma_f32_16x16x32_bf16(
                        aq[st & 1][ti], bq[st & 3][tj], acc[ti][tj], 0, 0, 0);
            __builtin_amdgcn_s_setprio(0);
            // Refill rings AFTER the MFMAs that consume these slots (clean WAR).
            if (st + 4 < 24) bload(st & 3, st + 4);
            if (st + 2 < 24) aload(st & 1, st + 2);
        }

        // ---- Per-half epilogue. C/D: col=lane&15 -> n, row=quad*4+r -> m.
        float esqv[2];
        #pragma unroll
        for (int tj = 0; tj < 2; ++tj) esqv[tj] = g_esq[w * 64 + h * 32 + tj * 16 + l16];
        #pragma unroll
        for (int ti = 0; ti < 4; ++ti)
            #pragma unroll
            for (int tj = 0; tj < 2; ++tj)
                #pragma unroll
                for (int r = 0; r < 4; ++r)
                    acc[ti][tj][r] = fmaf(-2.0f, acc[ti][tj][r], esqv[tj]);

        // Partition-local (min, idx, count-vs-own-min+TAU). Final gated merge
        // is exactly equivalent to the old global-threshold count:
        // flag <=> second-best overall < best + TAU.
        const int p = w * 2 + h;
        #pragma unroll
        for (int ti = 0; ti < 4; ++ti) {
            #pragma unroll
            for (int r = 0; r < 4; ++r) {
                float bv = acc[ti][0][r];
                int   bn = w * 64 + h * 32 + l16;      // n of tj=0
                {
                    float s = acc[ti][1][r];           // tj=1: n is larger -> strict <
                    if (s < bv) { bv = s; bn += 16; }
                }
                #pragma unroll
                for (int off = 1; off <= 8; off <<= 1) {   // butterfly over l16
                    float ov = __shfl_xor(bv, off);
                    int   on = __shfl_xor(bn, off);
                    if (ov < bv || (ov == bv && on < bn)) { bv = ov; bn = on; }
                }
                const float thr = bv + TAU;
                int c = ((acc[ti][0][r] < thr) ? 1 : 0) + ((acc[ti][1][r] < thr) ? 1 : 0);
                #pragma unroll
                for (int off = 1; off <= 8; off <<= 1) c += __shfl_xor(c, off);
                if (l16 == 0) {
                    const int m = ti * 16 + quad * 4 + r;
                    sP_mn[p][m] = bv;
                    sP_ic[p][m] = bn | (c << 16);
                }
            }
        }
    }
    __syncthreads();

    if (threadIdx.x < 64) {
        const int m = threadIdx.x;
        float gm = sP_mn[0][m];
        int   gi = sP_ic[0][m] & 0xFFFF;
        #pragma unroll
        for (int q = 1; q < 16; ++q) {
            float v = sP_mn[q][m];
            int  ii = sP_ic[q][m] & 0xFFFF;
            if (v < gm || (v == gm && ii < gi)) { gm = v; gi = ii; }
        }
        const float thr = gm + TAU;
        int ct = 0;
        #pragma unroll
        for (int q = 0; q < 16; ++q)
            if (sP_mn[q][m] < thr) ct += (sP_ic[q][m] >> 16);
        out[n0 + m] = gi;
        if (ct >= 2) {
            int pos = atomicAdd(&g_count, 1);
            g_list[pos] = n0 + m;
        }
    }
}

// Rescue: numpy-bit-exact (validated r4/r5/r8). One wave per flagged pixel.
// Untouched: its summation order is part of the bit-exactness contract.
__global__ __launch_bounds__(256) void rescue_kernel(const float* __restrict__ z,
                                                     int* __restrict__ out) {
    const int lane = threadIdx.x & 63;
    const int wg   = (int)blockIdx.x * 4 + (int)(threadIdx.x >> 6);
    const int nw   = (int)gridDim.x * 4;
    const int count = g_count;

    for (int it = wg; it < count; it += nw) {
        const int n = g_list[it];
        const float* zp = z + ((size_t)(n >> 10) << 18) + (n & 1023);

        float zf[4], xsq[4];
        #pragma unroll
        for (int q = 0; q < 4; ++q) zf[q] = zp[(size_t)((q << 6) + lane) << 10];
        #pragma unroll
        for (int q = 0; q < 4; ++q) xsq[q] = zf[q] * zf[q];

        // numpy pairwise zsq via shuffles (bit-exact, validated r5)
        const int j = lane & 7;
        float r0 = __shfl(xsq[0], j);
        #pragma unroll
        for (int t = 1; t < 8; ++t) r0 += __shfl(xsq[0], 8 * t + j);
        #pragma unroll
        for (int t = 0; t < 8; ++t) r0 += __shfl(xsq[1], 8 * t + j);
        float r1 = __shfl(xsq[2], j);
        #pragma unroll
        for (int t = 1; t < 8; ++t) r1 += __shfl(xsq[2], 8 * t + j);
        #pragma unroll
        for (int t = 0; t < 8; ++t) r1 += __shfl(xsq[3], 8 * t + j);
        r0 = r0 + __shfl_xor(r0, 1); r0 = r0 + __shfl_xor(r0, 2); r0 = r0 + __shfl_xor(r0, 4);
        r1 = r1 + __shfl_xor(r1, 1); r1 = r1 + __shfl_xor(r1, 2); r1 = r1 + __shfl_xor(r1, 4);
        const float zsq = r0 + r1;

        double a8a[8], a8b[8];
        #pragma unroll
        for (int jj = 0; jj < 8; ++jj) { a8a[jj] = 0.0; a8b[jj] = 0.0; }
        for (int dq = 0; dq < D_DIM / 4; ++dq) {
            const int d0 = dq * 4;
            double zd0 = (double)__shfl(zf[(d0    ) >> 6], (d0    ) & 63);
            double zd1 = (double)__shfl(zf[(d0 + 1) >> 6], (d0 + 1) & 63);
            double zd2 = (double)__shfl(zf[(d0 + 2) >> 6], (d0 + 2) & 63);
            double zd3 = (double)__shfl(zf[(d0 + 3) >> 6], (d0 + 3) & 63);
            #pragma unroll
            for (int jj = 0; jj < 8; ++jj) {
                float4 c4 = g_cbF4[dq * K_CODES + lane + (jj << 6)];
                a8a[jj] = fma((double)c4.x, zd0, a8a[jj]);
                a8a[jj] = fma((double)c4.y, zd1, a8a[jj]);
                a8b[jj] = fma((double)c4.z, zd2, a8b[jj]);
                a8b[jj] = fma((double)c4.w, zd3, a8b[jj]);
            }
        }

        float best = __builtin_inff(); int bi = 0x7FFFFFFF;
        #pragma unroll
        for (int jj = 0; jj < 8; ++jj) {
            int kk = lane + (jj << 6);
            float c32 = (float)(a8a[jj] + a8b[jj]);
            float t = zsq - 2.0f * c32;
            float dist = t + g_esq[kk];
            if (dist < best || (dist == best && kk < bi)) { best = dist; bi = kk; }
        }
        #pragma unroll
        for (int off = 32; off; off >>= 1) {
            float ob = __shfl_xor(best, off);
            int   oi = __shfl_xor(bi, off);
            if (ob < best || (ob == best && oi < bi)) { best = ob; bi = oi; }
        }
        if (lane == 0) out[n] = bi;
    }
}

extern "C" void kernel_launch(void* const* d_in, const int* in_sizes, int n_in,
                              void* d_out, int out_size, void* d_ws, size_t ws_size,
                              hipStream_t stream) {
    const float* z_e_x    = (const float*)d_in[0];   // [64, 256, 32, 32] fp32
    const float* codebook = (const float*)d_in[1];   // [512, 256] fp32
    int* out = (int*)d_out;                          // [65536] int32

    prep_cb<<<dim3(64), dim3(256), 0, stream>>>(codebook);
    pass1_fused<<<dim3(1024), dim3(512), 0, stream>>>(z_e_x, out);
    rescue_kernel<<<dim3(512), dim3(256), 0, stream>>>(z_e_x, out);
}

// Round 2
// 247.621 us; speedup vs baseline: 1.0158x; 1.0158x over previous
//
#include <hip/hip_runtime.h>

// contract(off): numpy-emulating fp32 ops (esq, rescue zsq/dist) must round mul
// and add separately. Explicit fmaf/fma and MFMA are unaffected.
#pragma clang fp contract(off)

#define K_CODES 512
#define D_DIM 256
#define NPIX 65536
#define TAU 3e-4f
#define STRA 264   // A LDS row stride in shorts: 528 B, 16B-aligned
// z layout [B=64, D=256, H*W=1024]; pixel n = b*1024 + hw.

typedef __attribute__((ext_vector_type(8))) short bf16x8;
typedef __attribute__((ext_vector_type(4))) float f32x4;

// B fragments pre-packed in wave-lane order (validated r8): index
// ((kc*32 + nb)*64 + lane)*8 holds B[n = nb*16 + (lane&15)][k = kc*32 + (lane>>4)*8 + j].
__device__ unsigned short g_bph[8 * 32 * 64 * 8];  // hi
__device__ unsigned short g_bpl[8 * 32 * 64 * 8];  // lo
__device__ float4 g_cbF4[(D_DIM / 4) * K_CODES];   // fp32 cb for rescue (exact)
__device__ float  g_esq[K_CODES];                  // numpy-pairwise fp32 ||e_k||^2
__device__ int    g_list[NPIX];
__device__ int    g_count;

static __device__ __forceinline__ unsigned short f2bf(float x) {
    unsigned u = __float_as_uint(x);
    return (unsigned short)((u + 0x7FFFu + ((u >> 16) & 1u)) >> 16);   // RNE
}
static __device__ __forceinline__ float bf2f(unsigned short h) {
    return __uint_as_float((unsigned)h << 16);
}

// 64 blocks x 256: thread = (k, kc, quad). Numerics byte-identical to the
// validated 16-block version (same f2bf, same esq pairwise order, same cbF4).
__global__ __launch_bounds__(256) void prep_cb(const float* __restrict__ cb) {
    if (blockIdx.x == 0 && threadIdx.x == 0) g_count = 0;
    const int gt   = blockIdx.x * 256 + threadIdx.x;   // 0..16383
    const int k    = gt >> 5;                          // 0..511
    const int sub  = gt & 31;
    const int kc   = sub >> 2;                         // 0..7
    const int quad = sub & 3;                          // 0..3
    const float* row = cb + k * D_DIM;
    const int nb = k >> 4, nl = k & 15;
    const int lane = quad * 16 + nl;

    unsigned short h8[8], l8[8];
    #pragma unroll
    for (int j = 0; j < 8; ++j) {
        float x = row[kc * 32 + quad * 8 + j];
        h8[j] = f2bf(x);
        l8[j] = f2bf(x - bf2f(h8[j]));   // x-hi exact (Sterbenz)
    }
    const int dst = ((kc * 32 + nb) * 64 + lane) * 8;
    *(uint4*)&g_bph[dst] = *(uint4*)&h8[0];
    *(uint4*)&g_bpl[dst] = *(uint4*)&l8[0];

    // cbF4 scatter distributed: each (k,sub) covers dq = 2*sub, 2*sub+1.
    #pragma unroll
    for (int u = 0; u < 2; ++u) {
        const int dq = sub * 2 + u;
        g_cbF4[dq * K_CODES + k] = make_float4(row[4*dq], row[4*dq+1], row[4*dq+2], row[4*dq+3]);
    }

    if (sub == 0) {
        // e_sq = np.sum(row*row): pairwise n=256 -> p(0:128)+p(128:256); 8 accums each.
        float s[2];
        for (int blk = 0; blk < 2; ++blk) {
            const float* a = row + blk * 128;
            float r[8];
            #pragma unroll
            for (int j = 0; j < 8; ++j) { float x = a[j]; r[j] = x * x; }
            for (int i = 8; i < 128; i += 8)
                #pragma unroll
                for (int j = 0; j < 8; ++j) { float x = a[i + j]; r[j] += x * x; }
            s[blk] = ((r[0] + r[1]) + (r[2] + r[3])) + ((r[4] + r[5]) + (r[6] + r[7]));
        }
        g_esq[k] = s[0] + s[1];
    }
}

// r10's validated structure (acc[4][4], VGPR 56+64acc = 120, 2 blocks/CU) with
// ONE register-neutral change: the 24-step loop is unrolled x2 with two NAMED
// B buffers (bA/bB). Same two B buffers r10 already held (bcur/bnxt), but:
//  - depth-2 flight: a B load issued at step st is consumed at st+2 (~260 cy,
//    covers the ~200-225 cy L2-hit latency; r10's 1-step flight did not), and
//  - zero ring-rotation movs (r10 paid 16 v_mov/step).
// MFMA accumulation order is bit-identical to r10 (steps ascending, ti->tj).
// setprio(1) around the MFMA cluster: the K-loop is barrier-free so the 4
// waves/SIMD drift into distinct phases (the regime where setprio pays, m191).
// DO NOT add a min-waves launch_bounds cap (r0 lesson: cap 128 forced spills,
// 90 MB scratch writes) and DO NOT grow rings past 2 B-buffers + 1 A-buffer
// (unified VGPR+AGPR budget for 2 blocks/CU is 128; r10 uses 120).
__global__ __launch_bounds__(512) void pass1_fused(const float* __restrict__ z,
                                                   int* __restrict__ out) {
    __shared__ unsigned short Az[2][64 * STRA];   // [0]=hi, [1]=lo ; [px][d]
    __shared__ float s_mn[8][64];
    __shared__ int   s_ixl[8][64];
    __shared__ float s_gm[64];
    __shared__ int   s_gi[64];
    __shared__ int   s_cnt[64];

    const int lane = threadIdx.x & 63;
    const int w    = __builtin_amdgcn_readfirstlane((int)(threadIdx.x >> 6));
    const int l16  = lane & 15, quad = lane >> 4;
    const int n0   = (int)blockIdx.x * 64;        // 64 | 1024 -> same b

    // ---- Prologue: stage A (validated r8). wave w: d-chunk [w*32,w*32+32), lane = px.
    {
        const float* zb = z + ((size_t)(n0 >> 10) << 18) + (n0 & 1023);
        const int px = lane, dc = w;
        #pragma unroll
        for (int half = 0; half < 2; ++half) {
            float x[16];
            #pragma unroll
            for (int j = 0; j < 16; ++j)
                x[j] = zb[(size_t)(dc * 32 + half * 16 + j) * 1024 + px]; // coalesced
            unsigned short hh[16], ll[16];
            #pragma unroll
            for (int j = 0; j < 16; ++j) {
                hh[j] = f2bf(x[j]);
                ll[j] = f2bf(x[j] - bf2f(hh[j]));
            }
            const int o = px * STRA + dc * 32 + half * 16;
            *(uint4*)&Az[0][o]     = *(uint4*)&hh[0];
            *(uint4*)&Az[0][o + 8] = *(uint4*)&hh[8];
            *(uint4*)&Az[1][o]     = *(uint4*)&ll[0];
            *(uint4*)&Az[1][o + 8] = *(uint4*)&ll[8];
        }
    }
    __syncthreads();

    f32x4 acc[4][4];
    #pragma unroll
    for (int i = 0; i < 4; ++i)
        #pragma unroll
        for (int j = 0; j < 4; ++j)
            acc[i][j] = (f32x4){0.f, 0.f, 0.f, 0.f};

    // step st: seg = st>>3 (0: zh*ch, 1: zh*cl, 2: zl*ch), kc = st&7.
    bf16x8 bA[4], bB[4];

#define BLOAD(dst_, st_) do {                                                   \
        const int kc_ = (st_) & 7;                                              \
        const unsigned short* bp_ = (((st_) >> 3) == 1) ? g_bpl : g_bph;        \
        _Pragma("unroll")                                                       \
        for (int tj = 0; tj < 4; ++tj)  /* 1 KB coalesced per wave, L2-hot */   \
            dst_[tj] = *(const bf16x8*)&bp_[((size_t)(kc_ * 32 + w * 4 + tj) * 64 + lane) * 8]; \
    } while (0)

#define MSTEP(breg_, st_) do {                                                  \
        const int seg_ = (st_) >> 3, kc_ = (st_) & 7;                           \
        const unsigned short* As_ = (seg_ == 2) ? &Az[1][0] : &Az[0][0];        \
        bf16x8 af_[4];                                                          \
        _Pragma("unroll")                                                       \
        for (int ti = 0; ti < 4; ++ti)  /* imm-offset ds_read_b128 x4 */        \
            af_[ti] = *(const bf16x8*)&As_[(ti * 16 + l16) * STRA + kc_ * 32 + quad * 8]; \
        __builtin_amdgcn_s_setprio(1);                                          \
        _Pragma("unroll")                                                       \
        for (int ti = 0; ti < 4; ++ti)                                          \
            _Pragma("unroll")                                                   \
            for (int tj = 0; tj < 4; ++tj)                                      \
                acc[ti][tj] = __builtin_amdgcn_mfma_f32_16x16x32_bf16(          \
                    af_[ti], breg_[tj], acc[ti][tj], 0, 0, 0);                  \
        __builtin_amdgcn_s_setprio(0);                                          \
    } while (0)

    BLOAD(bA, 0);
    BLOAD(bB, 1);

    // 11 double-steps (st 0..21) with always-valid prefetch, then 2-step tail.
    for (int su = 0; su < 11; ++su) {
        const int st0 = su * 2;
        MSTEP(bA, st0);     BLOAD(bA, st0 + 2);   // refill AFTER consume (WAR clean)
        MSTEP(bB, st0 + 1); BLOAD(bB, st0 + 3);
    }
    MSTEP(bA, 22);
    MSTEP(bB, 23);

#undef BLOAD
#undef MSTEP

    // ---- Epilogue (validated r6/r8/r10, verbatim). C/D: col=lane&15 -> n, row=quad*4+r -> m.
    float esqv[4];
    #pragma unroll
    for (int tj = 0; tj < 4; ++tj) esqv[tj] = g_esq[w * 64 + tj * 16 + l16];
    #pragma unroll
    for (int ti = 0; ti < 4; ++ti)
        #pragma unroll
        for (int tj = 0; tj < 4; ++tj)
            #pragma unroll
            for (int r = 0; r < 4; ++r)
                acc[ti][tj][r] = fmaf(-2.0f, acc[ti][tj][r], esqv[tj]);

    #pragma unroll
    for (int ti = 0; ti < 4; ++ti) {
        #pragma unroll
        for (int r = 0; r < 4; ++r) {
            float bv = __builtin_inff(); int bn = 0x7FFFFFFF;
            #pragma unroll
            for (int tj = 0; tj < 4; ++tj) {
                float s = acc[ti][tj][r];
                int nn = w * 64 + tj * 16 + l16;
                if (s < bv || (s == bv && nn < bn)) { bv = s; bn = nn; }
            }
            #pragma unroll
            for (int off = 1; off <= 8; off <<= 1) {
                float ov = __shfl_xor(bv, off); int on = __shfl_xor(bn, off);
                if (ov < bv || (ov == bv && on < bn)) { bv = ov; bn = on; }
            }
            if (l16 == 0) {
                int m = ti * 16 + quad * 4 + r;
                s_mn[w][m] = bv; s_ixl[w][m] = bn;
            }
        }
    }
    __syncthreads();

    if (threadIdx.x < 64) {
        int m = threadIdx.x;
        float gm = s_mn[0][m]; int gi = s_ixl[0][m];
        #pragma unroll
        for (int q = 1; q < 8; ++q) {
            float v = s_mn[q][m]; int ii = s_ixl[q][m];
            if (v < gm || (v == gm && ii < gi)) { gm = v; gi = ii; }
        }
        s_gm[m] = gm; s_gi[m] = gi; s_cnt[m] = 0;
    }
    __syncthreads();

    #pragma unroll
    for (int ti = 0; ti < 4; ++ti) {
        #pragma unroll
        for (int r = 0; r < 4; ++r) {
            int m = ti * 16 + quad * 4 + r;
            float thr = s_gm[m] + TAU;
            int c = 0;
            #pragma unroll
            for (int tj = 0; tj < 4; ++tj) c += (acc[ti][tj][r] < thr) ? 1 : 0;
            #pragma unroll
            for (int off = 1; off <= 8; off <<= 1) c += __shfl_xor(c, off);
            if (l16 == 0) atomicAdd(&s_cnt[m], c);
        }
    }
    __syncthreads();

    if (threadIdx.x < 64) {
        int m = threadIdx.x;
        out[n0 + m] = s_gi[m];
        if (s_cnt[m] >= 2) {
            int pos = atomicAdd(&g_count, 1);
            g_list[pos] = n0 + m;
        }
    }
}

// Rescue: numpy-bit-exact (validated r4/r5/r8). One wave per flagged pixel.
// Untouched: its summation order is part of the bit-exactness contract.
__global__ __launch_bounds__(256) void rescue_kernel(const float* __restrict__ z,
                                                     int* __restrict__ out) {
    const int lane = threadIdx.x & 63;
    const int wg   = (int)blockIdx.x * 4 + (int)(threadIdx.x >> 6);
    const int nw   = (int)gridDim.x * 4;
    const int count = g_count;

    for (int it = wg; it < count; it += nw) {
        const int n = g_list[it];
        const float* zp = z + ((size_t)(n >> 10) << 18) + (n & 1023);

        float zf[4], xsq[4];
        #pragma unroll
        for (int q = 0; q < 4; ++q) zf[q] = zp[(size_t)((q << 6) + lane) << 10];
        #pragma unroll
        for (int q = 0; q < 4; ++q) xsq[q] = zf[q] * zf[q];

        // numpy pairwise zsq via shuffles (bit-exact, validated r5)
        const int j = lane & 7;
        float r0 = __shfl(xsq[0], j);
        #pragma unroll
        for (int t = 1; t < 8; ++t) r0 += __shfl(xsq[0], 8 * t + j);
        #pragma unroll
        for (int t = 0; t < 8; ++t) r0 += __shfl(xsq[1], 8 * t + j);
        float r1 = __shfl(xsq[2], j);
        #pragma unroll
        for (int t = 1; t < 8; ++t) r1 += __shfl(xsq[2], 8 * t + j);
        #pragma unroll
        for (int t = 0; t < 8; ++t) r1 += __shfl(xsq[3], 8 * t + j);
        r0 = r0 + __shfl_xor(r0, 1); r0 = r0 + __shfl_xor(r0, 2); r0 = r0 + __shfl_xor(r0, 4);
        r1 = r1 + __shfl_xor(r1, 1); r1 = r1 + __shfl_xor(r1, 2); r1 = r1 + __shfl_xor(r1, 4);
        const float zsq = r0 + r1;

        double a8a[8], a8b[8];
        #pragma unroll
        for (int jj = 0; jj < 8; ++jj) { a8a[jj] = 0.0; a8b[jj] = 0.0; }
        for (int dq = 0; dq < D_DIM / 4; ++dq) {
            const int d0 = dq * 4;
            double zd0 = (double)__shfl(zf[(d0    ) >> 6], (d0    ) & 63);
            double zd1 = (double)__shfl(zf[(d0 + 1) >> 6], (d0 + 1) & 63);
            double zd2 = (double)__shfl(zf[(d0 + 2) >> 6], (d0 + 2) & 63);
            double zd3 = (double)__shfl(zf[(d0 + 3) >> 6], (d0 + 3) & 63);
            #pragma unroll
            for (int jj = 0; jj < 8; ++jj) {
                float4 c4 = g_cbF4[dq * K_CODES + lane + (jj << 6)];
                a8a[jj] = fma((double)c4.x, zd0, a8a[jj]);
                a8a[jj] = fma((double)c4.y, zd1, a8a[jj]);
                a8b[jj] = fma((double)c4.z, zd2, a8b[jj]);
                a8b[jj] = fma((double)c4.w, zd3, a8b[jj]);
            }
        }

        float best = __builtin_inff(); int bi = 0x7FFFFFFF;
        #pragma unroll
        for (int jj = 0; jj < 8; ++jj) {
            int kk = lane + (jj << 6);
            float c32 = (float)(a8a[jj] + a8b[jj]);
            float t = zsq - 2.0f * c32;
            float dist = t + g_esq[kk];
            if (dist < best || (dist == best && kk < bi)) { best = dist; bi = kk; }
        }
        #pragma unroll
        for (int off = 32; off; off >>= 1) {
            float ob = __shfl_xor(best, off);
            int   oi = __shfl_xor(bi, off);
            if (ob < best || (ob == best && oi < bi)) { best = ob; bi = oi; }
        }
        if (lane == 0) out[n] = bi;
    }
}

extern "C" void kernel_launch(void* const* d_in, const int* in_sizes, int n_in,
                              void* d_out, int out_size, void* d_ws, size_t ws_size,
                              hipStream_t stream) {
    const float* z_e_x    = (const float*)d_in[0];   // [64, 256, 32, 32] fp32
    const float* codebook = (const float*)d_in[1];   // [512, 256] fp32
    int* out = (int*)d_out;                          // [65536] int32

    prep_cb<<<dim3(64), dim3(256), 0, stream>>>(codebook);
    pass1_fused<<<dim3(1024), dim3(512), 0, stream>>>(z_e_x, out);
    rescue_kernel<<<dim3(512), dim3(256), 0, stream>>>(z_e_x, out);
}

// Round 3
// 225.516 us; speedup vs baseline: 1.1153x; 1.0980x over previous
//
#include <hip/hip_runtime.h>

// contract(off): numpy-emulating fp32 ops (esq, rescue zsq/dist) must round mul
// and add separately. Explicit fmaf/fma and MFMA are unaffected.
#pragma clang fp contract(off)

#define K_CODES 512
#define D_DIM 256
#define NPIX 65536
#define TAU 3e-4f
#define STRA 264   // A LDS row stride in shorts: 528 B, 16B-aligned
// z layout [B=64, D=256, H*W=1024]; pixel n = b*1024 + hw.

typedef __attribute__((ext_vector_type(8))) short bf16x8;
typedef __attribute__((ext_vector_type(4))) float f32x4;

// B fragments pre-packed in wave-lane order (validated r8): index
// ((kc*32 + nb)*64 + lane)*8 holds B[n = nb*16 + (lane&15)][k = kc*32 + (lane>>4)*8 + j].
__device__ unsigned short g_bph[8 * 32 * 64 * 8];  // hi
__device__ unsigned short g_bpl[8 * 32 * 64 * 8];  // lo
__device__ float4 g_cbF4[(D_DIM / 4) * K_CODES];   // fp32 cb for rescue (exact)
__device__ float  g_esq[K_CODES];                  // numpy-pairwise fp32 ||e_k||^2
__device__ int    g_list[NPIX];
__device__ int    g_count;

static __device__ __forceinline__ unsigned short f2bf(float x) {
    unsigned u = __float_as_uint(x);
    return (unsigned short)((u + 0x7FFFu + ((u >> 16) & 1u)) >> 16);   // RNE
}
static __device__ __forceinline__ float bf2f(unsigned short h) {
    return __uint_as_float((unsigned)h << 16);
}

// 64 blocks x 256: thread = (k, kc, quad). Numerics byte-identical to the
// validated 16-block version (same f2bf, same esq pairwise order, same cbF4
// values); 4x CU parallelism and the cbF4 scatter distributed over 32 threads
// per k instead of 1 (the 16-block version's scatter chain was the dominant
// cost of the ~142 us non-pass1 residual).
__global__ __launch_bounds__(256) void prep_cb(const float* __restrict__ cb) {
    if (blockIdx.x == 0 && threadIdx.x == 0) g_count = 0;
    const int gt   = blockIdx.x * 256 + threadIdx.x;   // 0..16383
    const int k    = gt >> 5;                          // 0..511
    const int sub  = gt & 31;
    const int kc   = sub >> 2;                         // 0..7
    const int quad = sub & 3;                          // 0..3
    const float* row = cb + k * D_DIM;
    const int nb = k >> 4, nl = k & 15;
    const int lane = quad * 16 + nl;

    unsigned short h8[8], l8[8];
    #pragma unroll
    for (int j = 0; j < 8; ++j) {
        float x = row[kc * 32 + quad * 8 + j];
        h8[j] = f2bf(x);
        l8[j] = f2bf(x - bf2f(h8[j]));   // x-hi exact (Sterbenz)
    }
    const int dst = ((kc * 32 + nb) * 64 + lane) * 8;
    *(uint4*)&g_bph[dst] = *(uint4*)&h8[0];
    *(uint4*)&g_bpl[dst] = *(uint4*)&l8[0];

    // cbF4 scatter distributed: each (k,sub) covers dq = 2*sub, 2*sub+1.
    #pragma unroll
    for (int u = 0; u < 2; ++u) {
        const int dq = sub * 2 + u;
        g_cbF4[dq * K_CODES + k] = make_float4(row[4*dq], row[4*dq+1], row[4*dq+2], row[4*dq+3]);
    }

    if (sub == 0) {
        // e_sq = np.sum(row*row): pairwise n=256 -> p(0:128)+p(128:256); 8 accums each.
        float s[2];
        for (int blk = 0; blk < 2; ++blk) {
            const float* a = row + blk * 128;
            float r[8];
            #pragma unroll
            for (int j = 0; j < 8; ++j) { float x = a[j]; r[j] = x * x; }
            for (int i = 8; i < 128; i += 8)
                #pragma unroll
                for (int j = 0; j < 8; ++j) { float x = a[i + j]; r[j] += x * x; }
            s[blk] = ((r[0] + r[1]) + (r[2] + r[3])) + ((r[4] + r[5]) + (r[6] + r[7]));
        }
        g_esq[k] = s[0] + s[1];
    }
}

// pass1: the r10 GOLDEN structure, verbatim (85 us, VGPR 56 + 64 acc = 120 ->
// exactly 2 blocks/CU). HARD-LEARNED CONSTRAINTS (r0/r1 of this session):
//  - arch VGPRs must stay <= 64: 2048-reg/16-wave budget minus acc[4][4]=64.
//    r1's x2-unrolled two-named-B-buffer variant hit 76 arch -> 1 block/CU ->
//    140 us. r0's launch_bounds(512,4) cap -> spills -> 90 MB scratch.
//  - Deeper B prefetch / setprio / ring-mov elimination give ZERO per-wave
//    gain (per-occupancy MFMA ratio 0.65 identical across r10/r1 variants);
//    occupancy is the ONLY lever that moved pass1. Do not restructure the
//    K-loop at HIP source level.
__global__ __launch_bounds__(512) void pass1_fused(const float* __restrict__ z,
                                                   int* __restrict__ out) {
    __shared__ unsigned short Az[2][64 * STRA];   // [0]=hi, [1]=lo ; [px][d]
    __shared__ float s_mn[8][64];
    __shared__ int   s_ixl[8][64];
    __shared__ float s_gm[64];
    __shared__ int   s_gi[64];
    __shared__ int   s_cnt[64];

    const int lane = threadIdx.x & 63;
    const int w    = __builtin_amdgcn_readfirstlane((int)(threadIdx.x >> 6));
    const int l16  = lane & 15, quad = lane >> 4;
    const int n0   = (int)blockIdx.x * 64;        // 64 | 1024 -> same b

    // ---- Prologue: stage A (validated r8). wave w: d-chunk [w*32,w*32+32), lane = px.
    {
        const float* zb = z + ((size_t)(n0 >> 10) << 18) + (n0 & 1023);
        const int px = lane, dc = w;
        #pragma unroll
        for (int half = 0; half < 2; ++half) {
            float x[16];
            #pragma unroll
            for (int j = 0; j < 16; ++j)
                x[j] = zb[(size_t)(dc * 32 + half * 16 + j) * 1024 + px]; // coalesced
            unsigned short h[16], l[16];
            #pragma unroll
            for (int j = 0; j < 16; ++j) {
                h[j] = f2bf(x[j]);
                l[j] = f2bf(x[j] - bf2f(h[j]));
            }
            const int o = px * STRA + dc * 32 + half * 16;
            *(uint4*)&Az[0][o]     = *(uint4*)&h[0];
            *(uint4*)&Az[0][o + 8] = *(uint4*)&h[8];
            *(uint4*)&Az[1][o]     = *(uint4*)&l[0];
            *(uint4*)&Az[1][o + 8] = *(uint4*)&l[8];
        }
    }
    __syncthreads();

    f32x4 acc[4][4];
    #pragma unroll
    for (int i = 0; i < 4; ++i)
        #pragma unroll
        for (int j = 0; j < 4; ++j)
            acc[i][j] = (f32x4){0.f, 0.f, 0.f, 0.f};

    // ---- K-loop: 24 steps, no barriers. seg0: zh*ch, seg1: zh*cl, seg2: zl*ch
    // (chain identical to validated r6/r8). B prefetched one step ahead.
    bf16x8 bcur[4];
    #pragma unroll
    for (int tj = 0; tj < 4; ++tj)
        bcur[tj] = *(const bf16x8*)&g_bph[((size_t)(0 * 32 + w * 4 + tj) * 64 + lane) * 8];

    for (int st = 0; st < 24; ++st) {
        const int seg = st >> 3;
        const int kc  = st & 7;
        const unsigned short* As = Az[(seg == 2) ? 1 : 0];

        bf16x8 bnxt[4];
        if (st < 23) {
            const int sp = st + 1;
            const unsigned short* bp = ((sp >> 3) == 1) ? g_bpl : g_bph;
            const int kcn = sp & 7;
            #pragma unroll
            for (int tj = 0; tj < 4; ++tj)   // 1 KB coalesced per wave, L2-hot
                bnxt[tj] = *(const bf16x8*)&bp[((size_t)(kcn * 32 + w * 4 + tj) * 64 + lane) * 8];
        }

        bf16x8 af[4];
        #pragma unroll
        for (int ti = 0; ti < 4; ++ti)
            af[ti] = *(const bf16x8*)&As[(ti * 16 + l16) * STRA + kc * 32 + quad * 8];

        #pragma unroll
        for (int ti = 0; ti < 4; ++ti)
            #pragma unroll
            for (int tj = 0; tj < 4; ++tj)
                acc[ti][tj] = __builtin_amdgcn_mfma_f32_16x16x32_bf16(
                    af[ti], bcur[tj], acc[ti][tj], 0, 0, 0);

        if (st < 23) {
            #pragma unroll
            for (int tj = 0; tj < 4; ++tj) bcur[tj] = bnxt[tj];
        }
    }

    // ---- Epilogue (validated r6/r8). C/D: col=lane&15 -> n, row=quad*4+r -> m.
    float esqv[4];
    #pragma unroll
    for (int tj = 0; tj < 4; ++tj) esqv[tj] = g_esq[w * 64 + tj * 16 + l16];
    #pragma unroll
    for (int ti = 0; ti < 4; ++ti)
        #pragma unroll
        for (int tj = 0; tj < 4; ++tj)
            #pragma unroll
            for (int r = 0; r < 4; ++r)
                acc[ti][tj][r] = fmaf(-2.0f, acc[ti][tj][r], esqv[tj]);

    #pragma unroll
    for (int ti = 0; ti < 4; ++ti) {
        #pragma unroll
        for (int r = 0; r < 4; ++r) {
            float bv = __builtin_inff(); int bn = 0x7FFFFFFF;
            #pragma unroll
            for (int tj = 0; tj < 4; ++tj) {
                float s = acc[ti][tj][r];
                int nn = w * 64 + tj * 16 + l16;
                if (s < bv || (s == bv && nn < bn)) { bv = s; bn = nn; }
            }
            #pragma unroll
            for (int off = 1; off <= 8; off <<= 1) {
                float ov = __shfl_xor(bv, off); int on = __shfl_xor(bn, off);
                if (ov < bv || (ov == bv && on < bn)) { bv = ov; bn = on; }
            }
            if (l16 == 0) {
                int m = ti * 16 + quad * 4 + r;
                s_mn[w][m] = bv; s_ixl[w][m] = bn;
            }
        }
    }
    __syncthreads();

    if (threadIdx.x < 64) {
        int m = threadIdx.x;
        float gm = s_mn[0][m]; int gi = s_ixl[0][m];
        #pragma unroll
        for (int q = 1; q < 8; ++q) {
            float v = s_mn[q][m]; int ii = s_ixl[q][m];
            if (v < gm || (v == gm && ii < gi)) { gm = v; gi = ii; }
        }
        s_gm[m] = gm; s_gi[m] = gi; s_cnt[m] = 0;
    }
    __syncthreads();

    #pragma unroll
    for (int ti = 0; ti < 4; ++ti) {
        #pragma unroll
        for (int r = 0; r < 4; ++r) {
            int m = ti * 16 + quad * 4 + r;
            float thr = s_gm[m] + TAU;
            int c = 0;
            #pragma unroll
            for (int tj = 0; tj < 4; ++tj) c += (acc[ti][tj][r] < thr) ? 1 : 0;
            #pragma unroll
            for (int off = 1; off <= 8; off <<= 1) c += __shfl_xor(c, off);
            if (l16 == 0) atomicAdd(&s_cnt[m], c);
        }
    }
    __syncthreads();

    if (threadIdx.x < 64) {
        int m = threadIdx.x;
        out[n0 + m] = s_gi[m];
        if (s_cnt[m] >= 2) {
            int pos = atomicAdd(&g_count, 1);
            g_list[pos] = n0 + m;
        }
    }
}

// Rescue: numpy-bit-exact (validated r4/r5/r8). One wave per flagged pixel.
// Untouched: its summation order is part of the bit-exactness contract.
__global__ __launch_bounds__(256) void rescue_kernel(const float* __restrict__ z,
                                                     int* __restrict__ out) {
    const int lane = threadIdx.x & 63;
    const int wg   = (int)blockIdx.x * 4 + (int)(threadIdx.x >> 6);
    const int nw   = (int)gridDim.x * 4;
    const int count = g_count;

    for (int it = wg; it < count; it += nw) {
        const int n = g_list[it];
        const float* zp = z + ((size_t)(n >> 10) << 18) + (n & 1023);

        float zf[4], xsq[4];
        #pragma unroll
        for (int q = 0; q < 4; ++q) zf[q] = zp[(size_t)((q << 6) + lane) << 10];
        #pragma unroll
        for (int q = 0; q < 4; ++q) xsq[q] = zf[q] * zf[q];

        // numpy pairwise zsq via shuffles (bit-exact, validated r5)
        const int j = lane & 7;
        float r0 = __shfl(xsq[0], j);
        #pragma unroll
        for (int t = 1; t < 8; ++t) r0 += __shfl(xsq[0], 8 * t + j);
        #pragma unroll
        for (int t = 0; t < 8; ++t) r0 += __shfl(xsq[1], 8 * t + j);
        float r1 = __shfl(xsq[2], j);
        #pragma unroll
        for (int t = 1; t < 8; ++t) r1 += __shfl(xsq[2], 8 * t + j);
        #pragma unroll
        for (int t = 0; t < 8; ++t) r1 += __shfl(xsq[3], 8 * t + j);
        r0 = r0 + __shfl_xor(r0, 1); r0 = r0 + __shfl_xor(r0, 2); r0 = r0 + __shfl_xor(r0, 4);
        r1 = r1 + __shfl_xor(r1, 1); r1 = r1 + __shfl_xor(r1, 2); r1 = r1 + __shfl_xor(r1, 4);
        const float zsq = r0 + r1;

        double a8a[8], a8b[8];
        #pragma unroll
        for (int jj = 0; jj < 8; ++jj) { a8a[jj] = 0.0; a8b[jj] = 0.0; }
        for (int dq = 0; dq < D_DIM / 4; ++dq) {
            const int d0 = dq * 4;
            double zd0 = (double)__shfl(zf[(d0    ) >> 6], (d0    ) & 63);
            double zd1 = (double)__shfl(zf[(d0 + 1) >> 6], (d0 + 1) & 63);
            double zd2 = (double)__shfl(zf[(d0 + 2) >> 6], (d0 + 2) & 63);
            double zd3 = (double)__shfl(zf[(d0 + 3) >> 6], (d0 + 3) & 63);
            #pragma unroll
            for (int jj = 0; jj < 8; ++jj) {
                float4 c4 = g_cbF4[dq * K_CODES + lane + (jj << 6)];
                a8a[jj] = fma((double)c4.x, zd0, a8a[jj]);
                a8a[jj] = fma((double)c4.y, zd1, a8a[jj]);
                a8b[jj] = fma((double)c4.z, zd2, a8b[jj]);
                a8b[jj] = fma((double)c4.w, zd3, a8b[jj]);
            }
        }

        float best = __builtin_inff(); int bi = 0x7FFFFFFF;
        #pragma unroll
        for (int jj = 0; jj < 8; ++jj) {
            int kk = lane + (jj << 6);
            float c32 = (float)(a8a[jj] + a8b[jj]);
            float t = zsq - 2.0f * c32;
            float dist = t + g_esq[kk];
            if (dist < best || (dist == best && kk < bi)) { best = dist; bi = kk; }
        }
        #pragma unroll
        for (int off = 32; off; off >>= 1) {
            float ob = __shfl_xor(best, off);
            int   oi = __shfl_xor(bi, off);
            if (ob < best || (ob == best && oi < bi)) { best = ob; bi = oi; }
        }
        if (lane == 0) out[n] = bi;
    }
}

extern "C" void kernel_launch(void* const* d_in, const int* in_sizes, int n_in,
                              void* d_out, int out_size, void* d_ws, size_t ws_size,
                              hipStream_t stream) {
    const float* z_e_x    = (const float*)d_in[0];   // [64, 256, 32, 32] fp32
    const float* codebook = (const float*)d_in[1];   // [512, 256] fp32
    int* out = (int*)d_out;                          // [65536] int32

    prep_cb<<<dim3(64), dim3(256), 0, stream>>>(codebook);
    pass1_fused<<<dim3(1024), dim3(512), 0, stream>>>(z_e_x, out);
    rescue_kernel<<<dim3(512), dim3(256), 0, stream>>>(z_e_x, out);
}

// Round 4
// 179.015 us; speedup vs baseline: 1.4050x; 1.2598x over previous
//
#include <hip/hip_runtime.h>

// contract(off): numpy-emulating fp32 ops (esq, rescue zsq/dist) must round mul
// and add separately. Explicit fmaf/fma and MFMA are unaffected.
#pragma clang fp contract(off)

#define K_CODES 512
#define D_DIM 256
#define NPIX 65536
#define TAU 3e-4f
#define STRA 264   // A LDS row stride in shorts: 528 B, 16B-aligned
#define CMAX 16    // max stored rescue candidates per pixel (overflow -> full scan)
// z layout [B=64, D=256, H*W=1024]; pixel n = b*1024 + hw.

typedef __attribute__((ext_vector_type(8))) short bf16x8;
typedef __attribute__((ext_vector_type(4))) float f32x4;

// B fragments pre-packed in wave-lane order (validated r8): index
// ((kc*32 + nb)*64 + lane)*8 holds B[n = nb*16 + (lane&15)][k = kc*32 + (lane>>4)*8 + j].
__device__ unsigned short g_bph[8 * 32 * 64 * 8];  // hi
__device__ unsigned short g_bpl[8 * 32 * 64 * 8];  // lo
__device__ float4 g_cbF4[(D_DIM / 4) * K_CODES];   // fp32 cb for rescue (exact)
__device__ float  g_esq[K_CODES];                  // numpy-pairwise fp32 ||e_k||^2
__device__ int    g_list[NPIX];                    // n | (ncand<<16) | overflow<<31
__device__ int    g_cand[NPIX * CMAX];             // candidate code ids per flagged pixel
__device__ int    g_count;

static __device__ __forceinline__ unsigned short f2bf(float x) {
    unsigned u = __float_as_uint(x);
    return (unsigned short)((u + 0x7FFFu + ((u >> 16) & 1u)) >> 16);   // RNE
}
static __device__ __forceinline__ float bf2f(unsigned short h) {
    return __uint_as_float((unsigned)h << 16);
}

// 64 blocks x 256: thread = (k, kc, quad). Numerics byte-identical to the
// validated 16-block version (same f2bf, same esq pairwise order, same cbF4).
__global__ __launch_bounds__(256) void prep_cb(const float* __restrict__ cb) {
    if (blockIdx.x == 0 && threadIdx.x == 0) g_count = 0;
    const int gt   = blockIdx.x * 256 + threadIdx.x;   // 0..16383
    const int k    = gt >> 5;                          // 0..511
    const int sub  = gt & 31;
    const int kc   = sub >> 2;                         // 0..7
    const int quad = sub & 3;                          // 0..3
    const float* row = cb + k * D_DIM;
    const int nb = k >> 4, nl = k & 15;
    const int lane = quad * 16 + nl;

    unsigned short h8[8], l8[8];
    #pragma unroll
    for (int j = 0; j < 8; ++j) {
        float x = row[kc * 32 + quad * 8 + j];
        h8[j] = f2bf(x);
        l8[j] = f2bf(x - bf2f(h8[j]));   // x-hi exact (Sterbenz)
    }
    const int dst = ((kc * 32 + nb) * 64 + lane) * 8;
    *(uint4*)&g_bph[dst] = *(uint4*)&h8[0];
    *(uint4*)&g_bpl[dst] = *(uint4*)&l8[0];

    // cbF4 scatter distributed: each (k,sub) covers dq = 2*sub, 2*sub+1.
    #pragma unroll
    for (int u = 0; u < 2; ++u) {
        const int dq = sub * 2 + u;
        g_cbF4[dq * K_CODES + k] = make_float4(row[4*dq], row[4*dq+1], row[4*dq+2], row[4*dq+3]);
    }

    if (sub == 0) {
        // e_sq = np.sum(row*row): pairwise n=256 -> p(0:128)+p(128:256); 8 accums each.
        float s[2];
        for (int blk = 0; blk < 2; ++blk) {
            const float* a = row + blk * 128;
            float r[8];
            #pragma unroll
            for (int j = 0; j < 8; ++j) { float x = a[j]; r[j] = x * x; }
            for (int i = 8; i < 128; i += 8)
                #pragma unroll
                for (int j = 0; j < 8; ++j) { float x = a[i + j]; r[j] += x * x; }
            s[blk] = ((r[0] + r[1]) + (r[2] + r[3])) + ((r[4] + r[5]) + (r[6] + r[7]));
        }
        g_esq[k] = s[0] + s[1];
    }
}

// pass1: the r10 GOLDEN K-loop, verbatim (85 us, VGPR 56 + 64 acc = 120 ->
// exactly 2 blocks/CU). HARD-LEARNED CONSTRAINTS (r0/r1 of this session):
//  - arch VGPRs must stay <= 64 (2048/16-wave budget minus acc[4][4]=64).
//    r1's x2-unroll hit 76 arch -> 1 block/CU -> 140 us. r0's
//    launch_bounds(512,4) cap -> spills -> 90 MB scratch.
//  - Deeper prefetch / setprio / ring-mov elimination give ZERO per-wave gain
//    (per-occupancy MFMA ratio 0.65 identical across variants). Occupancy is
//    the only lever that moved pass1. Do not restructure the K-loop.
// Epilogue change this round: the count pass now ALSO records the candidate
// code set {dist < min+TAU} (<=CMAX, overflow->flag) so rescue can recompute
// only those codes instead of all 512. Provably identical result: any numpy
// minimizer k* has our_dist(k*) <= our_min + 2*eps < our_min + TAU.
__global__ __launch_bounds__(512) void pass1_fused(const float* __restrict__ z,
                                                   int* __restrict__ out) {
    __shared__ unsigned short Az[2][64 * STRA];   // [0]=hi, [1]=lo ; [px][d]
    __shared__ float s_mn[8][64];
    __shared__ int   s_ixl[8][64];
    __shared__ float s_gm[64];
    __shared__ int   s_gi[64];
    __shared__ int   s_ccn[64];
    __shared__ int   s_cand[64][CMAX];

    const int lane = threadIdx.x & 63;
    const int w    = __builtin_amdgcn_readfirstlane((int)(threadIdx.x >> 6));
    const int l16  = lane & 15, quad = lane >> 4;
    const int n0   = (int)blockIdx.x * 64;        // 64 | 1024 -> same b

    // ---- Prologue: stage A (validated r8). wave w: d-chunk [w*32,w*32+32), lane = px.
    {
        const float* zb = z + ((size_t)(n0 >> 10) << 18) + (n0 & 1023);
        const int px = lane, dc = w;
        #pragma unroll
        for (int half = 0; half < 2; ++half) {
            float x[16];
            #pragma unroll
            for (int j = 0; j < 16; ++j)
                x[j] = zb[(size_t)(dc * 32 + half * 16 + j) * 1024 + px]; // coalesced
            unsigned short h[16], l[16];
            #pragma unroll
            for (int j = 0; j < 16; ++j) {
                h[j] = f2bf(x[j]);
                l[j] = f2bf(x[j] - bf2f(h[j]));
            }
            const int o = px * STRA + dc * 32 + half * 16;
            *(uint4*)&Az[0][o]     = *(uint4*)&h[0];
            *(uint4*)&Az[0][o + 8] = *(uint4*)&h[8];
            *(uint4*)&Az[1][o]     = *(uint4*)&l[0];
            *(uint4*)&Az[1][o + 8] = *(uint4*)&l[8];
        }
    }
    __syncthreads();

    f32x4 acc[4][4];
    #pragma unroll
    for (int i = 0; i < 4; ++i)
        #pragma unroll
        for (int j = 0; j < 4; ++j)
            acc[i][j] = (f32x4){0.f, 0.f, 0.f, 0.f};

    // ---- K-loop: 24 steps, no barriers. seg0: zh*ch, seg1: zh*cl, seg2: zl*ch
    // (chain identical to validated r6/r8). B prefetched one step ahead.
    bf16x8 bcur[4];
    #pragma unroll
    for (int tj = 0; tj < 4; ++tj)
        bcur[tj] = *(const bf16x8*)&g_bph[((size_t)(0 * 32 + w * 4 + tj) * 64 + lane) * 8];

    for (int st = 0; st < 24; ++st) {
        const int seg = st >> 3;
        const int kc  = st & 7;
        const unsigned short* As = Az[(seg == 2) ? 1 : 0];

        bf16x8 bnxt[4];
        if (st < 23) {
            const int sp = st + 1;
            const unsigned short* bp = ((sp >> 3) == 1) ? g_bpl : g_bph;
            const int kcn = sp & 7;
            #pragma unroll
            for (int tj = 0; tj < 4; ++tj)   // 1 KB coalesced per wave, L2-hot
                bnxt[tj] = *(const bf16x8*)&bp[((size_t)(kcn * 32 + w * 4 + tj) * 64 + lane) * 8];
        }

        bf16x8 af[4];
        #pragma unroll
        for (int ti = 0; ti < 4; ++ti)
            af[ti] = *(const bf16x8*)&As[(ti * 16 + l16) * STRA + kc * 32 + quad * 8];

        #pragma unroll
        for (int ti = 0; ti < 4; ++ti)
            #pragma unroll
            for (int tj = 0; tj < 4; ++tj)
                acc[ti][tj] = __builtin_amdgcn_mfma_f32_16x16x32_bf16(
                    af[ti], bcur[tj], acc[ti][tj], 0, 0, 0);

        if (st < 23) {
            #pragma unroll
            for (int tj = 0; tj < 4; ++tj) bcur[tj] = bnxt[tj];
        }
    }

    // ---- Epilogue. C/D: col=lane&15 -> n, row=quad*4+r -> m.
    float esqv[4];
    #pragma unroll
    for (int tj = 0; tj < 4; ++tj) esqv[tj] = g_esq[w * 64 + tj * 16 + l16];
    #pragma unroll
    for (int ti = 0; ti < 4; ++ti)
        #pragma unroll
        for (int tj = 0; tj < 4; ++tj)
            #pragma unroll
            for (int r = 0; r < 4; ++r)
                acc[ti][tj][r] = fmaf(-2.0f, acc[ti][tj][r], esqv[tj]);

    #pragma unroll
    for (int ti = 0; ti < 4; ++ti) {
        #pragma unroll
        for (int r = 0; r < 4; ++r) {
            float bv = __builtin_inff(); int bn = 0x7FFFFFFF;
            #pragma unroll
            for (int tj = 0; tj < 4; ++tj) {
                float s = acc[ti][tj][r];
                int nn = w * 64 + tj * 16 + l16;
                if (s < bv || (s == bv && nn < bn)) { bv = s; bn = nn; }
            }
            #pragma unroll
            for (int off = 1; off <= 8; off <<= 1) {
                float ov = __shfl_xor(bv, off); int on = __shfl_xor(bn, off);
                if (ov < bv || (ov == bv && on < bn)) { bv = ov; bn = on; }
            }
            if (l16 == 0) {
                int m = ti * 16 + quad * 4 + r;
                s_mn[w][m] = bv; s_ixl[w][m] = bn;
            }
        }
    }
    __syncthreads();

    if (threadIdx.x < 64) {
        int m = threadIdx.x;
        float gm = s_mn[0][m]; int gi = s_ixl[0][m];
        #pragma unroll
        for (int q = 1; q < 8; ++q) {
            float v = s_mn[q][m]; int ii = s_ixl[q][m];
            if (v < gm || (v == gm && ii < gi)) { gm = v; gi = ii; }
        }
        s_gm[m] = gm; s_gi[m] = gi; s_ccn[m] = 0;
    }
    __syncthreads();

    // Candidate-append pass (replaces the old count pass; s_ccn ends equal to
    // the old s_cnt: #codes with dist < gm+TAU, which always includes the min).
    // List order is atomic-nondeterministic; rescue argmins over all entries
    // with (dist, code-id) lexicographic order, so order is irrelevant.
    #pragma unroll
    for (int ti = 0; ti < 4; ++ti) {
        #pragma unroll
        for (int r = 0; r < 4; ++r) {
            const int m = ti * 16 + quad * 4 + r;
            const float thr = s_gm[m] + TAU;
            #pragma unroll
            for (int tj = 0; tj < 4; ++tj) {
                if (acc[ti][tj][r] < thr) {
                    int slot = atomicAdd(&s_ccn[m], 1);
                    if (slot < CMAX) s_cand[m][slot] = w * 64 + tj * 16 + l16;
                }
            }
        }
    }
    __syncthreads();

    if (threadIdx.x < 64) {
        int m = threadIdx.x;
        out[n0 + m] = s_gi[m];
        int cnt = s_ccn[m];
        if (cnt >= 2) {
            int pos = atomicAdd(&g_count, 1);
            int ncS = cnt > CMAX ? CMAX : cnt;
            g_list[pos] = (n0 + m) | (ncS << 16) | (cnt > CMAX ? (int)0x80000000 : 0);
            for (int i = 0; i < ncS; ++i) g_cand[pos * CMAX + i] = s_cand[m][i];
        }
    }
}

// Rescue: numpy-bit-exact (validated r4/r5/r8). One wave per flagged pixel.
// NEW: only the recorded candidate codes are recomputed (lane i -> cand[i]);
// per-code math (zsq shuffle pattern, a8a/a8b double-FMA split, final
// fp32 rounding chain) is VERBATIM the validated full-scan body, so each
// candidate's dist is bit-identical to what the full scan would produce.
// The TAU guarantee puts every possible numpy argmin in the candidate set,
// so the restricted argmin equals the full argmin. Overflow (>CMAX) pixels
// take the original full-512 path, preserved below.
__global__ __launch_bounds__(256) void rescue_kernel(const float* __restrict__ z,
                                                     int* __restrict__ out) {
    const int lane = threadIdx.x & 63;
    const int wg   = (int)blockIdx.x * 4 + (int)(threadIdx.x >> 6);
    const int nw   = (int)gridDim.x * 4;
    const int count = g_count;

    for (int it = wg; it < count; it += nw) {
        const int entry = g_list[it];
        const int n  = entry & 0xFFFF;
        const int nc = (entry >> 16) & 0x1F;
        const bool full = entry < 0;               // overflow -> full scan
        const float* zp = z + ((size_t)(n >> 10) << 18) + (n & 1023);

        float zf[4], xsq[4];
        #pragma unroll
        for (int q = 0; q < 4; ++q) zf[q] = zp[(size_t)((q << 6) + lane) << 10];
        #pragma unroll
        for (int q = 0; q < 4; ++q) xsq[q] = zf[q] * zf[q];

        // numpy pairwise zsq via shuffles (bit-exact, validated r5)
        const int j = lane & 7;
        float r0 = __shfl(xsq[0], j);
        #pragma unroll
        for (int t = 1; t < 8; ++t) r0 += __shfl(xsq[0], 8 * t + j);
        #pragma unroll
        for (int t = 0; t < 8; ++t) r0 += __shfl(xsq[1], 8 * t + j);
        float r1 = __shfl(xsq[2], j);
        #pragma unroll
        for (int t = 1; t < 8; ++t) r1 += __shfl(xsq[2], 8 * t + j);
        #pragma unroll
        for (int t = 0; t < 8; ++t) r1 += __shfl(xsq[3], 8 * t + j);
        r0 = r0 + __shfl_xor(r0, 1); r0 = r0 + __shfl_xor(r0, 2); r0 = r0 + __shfl_xor(r0, 4);
        r1 = r1 + __shfl_xor(r1, 1); r1 = r1 + __shfl_xor(r1, 2); r1 = r1 + __shfl_xor(r1, 4);
        const float zsq = r0 + r1;

        float best = __builtin_inff(); int bi = 0x7FFFFFFF;

        if (!full) {
            // Candidate path: lane i handles candidate i (lanes >= nc duplicate
            // candidate 0 -- idempotent under (dist, idx) min-reduce).
            const int kk = g_cand[it * CMAX + (lane < nc ? lane : 0)];
            double a8a = 0.0, a8b = 0.0;
            for (int dq = 0; dq < D_DIM / 4; ++dq) {
                const int d0 = dq * 4;
                double zd0 = (double)__shfl(zf[(d0    ) >> 6], (d0    ) & 63);
                double zd1 = (double)__shfl(zf[(d0 + 1) >> 6], (d0 + 1) & 63);
                double zd2 = (double)__shfl(zf[(d0 + 2) >> 6], (d0 + 2) & 63);
                double zd3 = (double)__shfl(zf[(d0 + 3) >> 6], (d0 + 3) & 63);
                float4 c4 = g_cbF4[dq * K_CODES + kk];
                a8a = fma((double)c4.x, zd0, a8a);
                a8a = fma((double)c4.y, zd1, a8a);
                a8b = fma((double)c4.z, zd2, a8b);
                a8b = fma((double)c4.w, zd3, a8b);
            }
            float c32 = (float)(a8a + a8b);
            float t = zsq - 2.0f * c32;
            best = t + g_esq[kk];
            bi = kk;
        } else {
            // Original full-512 path, verbatim (overflow fallback).
            double a8a[8], a8b[8];
            #pragma unroll
            for (int jj = 0; jj < 8; ++jj) { a8a[jj] = 0.0; a8b[jj] = 0.0; }
            for (int dq = 0; dq < D_DIM / 4; ++dq) {
                const int d0 = dq * 4;
                double zd0 = (double)__shfl(zf[(d0    ) >> 6], (d0    ) & 63);
                double zd1 = (double)__shfl(zf[(d0 + 1) >> 6], (d0 + 1) & 63);
                double zd2 = (double)__shfl(zf[(d0 + 2) >> 6], (d0 + 2) & 63);
                double zd3 = (double)__shfl(zf[(d0 + 3) >> 6], (d0 + 3) & 63);
                #pragma unroll
                for (int jj = 0; jj < 8; ++jj) {
                    float4 c4 = g_cbF4[dq * K_CODES + lane + (jj << 6)];
                    a8a[jj] = fma((double)c4.x, zd0, a8a[jj]);
                    a8a[jj] = fma((double)c4.y, zd1, a8a[jj]);
                    a8b[jj] = fma((double)c4.z, zd2, a8b[jj]);
                    a8b[jj] = fma((double)c4.w, zd3, a8b[jj]);
                }
            }
            #pragma unroll
            for (int jj = 0; jj < 8; ++jj) {
                int kk = lane + (jj << 6);
                float c32 = (float)(a8a[jj] + a8b[jj]);
                float t = zsq - 2.0f * c32;
                float dist = t + g_esq[kk];
                if (dist < best || (dist == best && kk < bi)) { best = dist; bi = kk; }
            }
        }

        #pragma unroll
        for (int off = 32; off; off >>= 1) {
            float ob = __shfl_xor(best, off);
            int   oi = __shfl_xor(bi, off);
            if (ob < best || (ob == best && oi < bi)) { best = ob; bi = oi; }
        }
        if (lane == 0) out[n] = bi;
    }
}

extern "C" void kernel_launch(void* const* d_in, const int* in_sizes, int n_in,
                              void* d_out, int out_size, void* d_ws, size_t ws_size,
                              hipStream_t stream) {
    const float* z_e_x    = (const float*)d_in[0];   // [64, 256, 32, 32] fp32
    const float* codebook = (const float*)d_in[1];   // [512, 256] fp32
    int* out = (int*)d_out;                          // [65536] int32

    prep_cb<<<dim3(64), dim3(256), 0, stream>>>(codebook);
    pass1_fused<<<dim3(1024), dim3(512), 0, stream>>>(z_e_x, out);
    rescue_kernel<<<dim3(512), dim3(256), 0, stream>>>(z_e_x, out);
}

// Round 6
// 177.045 us; speedup vs baseline: 1.4207x; 1.0111x over previous
//
#include <hip/hip_runtime.h>

// contract(off): numpy-emulating fp32 ops (esq, rescue zsq/dist) must round mul
// and add separately. Explicit fmaf/fma and MFMA are unaffected.
#pragma clang fp contract(off)

#define K_CODES 512
#define D_DIM 256
#define NPIX 65536
#define TAU 3e-4f
#define STRA 264   // A LDS row stride in shorts: 528 B, 16B-aligned
#define CMAX 16    // max stored rescue candidates per pixel (overflow -> full scan)
// z layout [B=64, D=256, H*W=1024]; pixel n = b*1024 + hw.

typedef __attribute__((ext_vector_type(8))) short bf16x8;
typedef __attribute__((ext_vector_type(4))) float f32x4;

// B fragments pre-packed in wave-lane order (validated r8): index
// ((kc*32 + nb)*64 + lane)*8 holds B[n = nb*16 + (lane&15)][k = kc*32 + (lane>>4)*8 + j].
__device__ unsigned short g_bph[8 * 32 * 64 * 8];  // hi
__device__ unsigned short g_bpl[8 * 32 * 64 * 8];  // lo
__device__ float4 g_cbF4[(D_DIM / 4) * K_CODES];   // fp32 cb for rescue (exact)
__device__ float  g_esq[K_CODES];                  // numpy-pairwise fp32 ||e_k||^2
__device__ int    g_list[NPIX];                    // n | (ncand<<16) | overflow<<31
__device__ int    g_cand[NPIX * CMAX];             // candidate code ids per flagged pixel
__device__ int    g_count;

// SESSION LEDGER (do not re-try):
//  r0: acc[4][2] two-half split + launch_bounds(512,4) -> spills (90 MB scratch), 112 us. REVERTED.
//  r1: x2-unrolled K-loop, 2 named B bufs, setprio -> VGPR 76+64 > 128 budget -> 1 block/CU, 140 us. REVERTED.
//  r3 (THIS KERNEL): candidate-set rescue (scan ~3 codes instead of 512). PASSED, 179.0 us.
//  r4: rescue fused INTO pass1 -> nondeterministic post-timing divergence (absmax 512,
//      poison-retained output). Root cause never identified despite exhaustive audit
//      (suspects: same-address cross-wave store ordering, fused-epilogue codegen).
//      DO NOT re-attempt in-kernel rescue without a causal theory + race screen.

static __device__ __forceinline__ unsigned short f2bf(float x) {
    unsigned u = __float_as_uint(x);
    return (unsigned short)((u + 0x7FFFu + ((u >> 16) & 1u)) >> 16);   // RNE
}
static __device__ __forceinline__ float bf2f(unsigned short h) {
    return __uint_as_float((unsigned)h << 16);
}

// 64 blocks x 256: thread = (k, kc, quad). Numerics byte-identical to the
// validated 16-block version (same f2bf, same esq pairwise order, same cbF4).
__global__ __launch_bounds__(256) void prep_cb(const float* __restrict__ cb) {
    if (blockIdx.x == 0 && threadIdx.x == 0) g_count = 0;
    const int gt   = blockIdx.x * 256 + threadIdx.x;   // 0..16383
    const int k    = gt >> 5;                          // 0..511
    const int sub  = gt & 31;
    const int kc   = sub >> 2;                         // 0..7
    const int quad = sub & 3;                          // 0..3
    const float* row = cb + k * D_DIM;
    const int nb = k >> 4, nl = k & 15;
    const int lane = quad * 16 + nl;

    unsigned short h8[8], l8[8];
    #pragma unroll
    for (int j = 0; j < 8; ++j) {
        float x = row[kc * 32 + quad * 8 + j];
        h8[j] = f2bf(x);
        l8[j] = f2bf(x - bf2f(h8[j]));   // x-hi exact (Sterbenz)
    }
    const int dst = ((kc * 32 + nb) * 64 + lane) * 8;
    *(uint4*)&g_bph[dst] = *(uint4*)&h8[0];
    *(uint4*)&g_bpl[dst] = *(uint4*)&l8[0];

    // cbF4 scatter distributed: each (k,sub) covers dq = 2*sub, 2*sub+1.
    #pragma unroll
    for (int u = 0; u < 2; ++u) {
        const int dq = sub * 2 + u;
        g_cbF4[dq * K_CODES + k] = make_float4(row[4*dq], row[4*dq+1], row[4*dq+2], row[4*dq+3]);
    }

    if (sub == 0) {
        // e_sq = np.sum(row*row): pairwise n=256 -> p(0:128)+p(128:256); 8 accums each.
        float s[2];
        for (int blk = 0; blk < 2; ++blk) {
            const float* a = row + blk * 128;
            float r[8];
            #pragma unroll
            for (int j = 0; j < 8; ++j) { float x = a[j]; r[j] = x * x; }
            for (int i = 8; i < 128; i += 8)
                #pragma unroll
                for (int j = 0; j < 8; ++j) { float x = a[i + j]; r[j] += x * x; }
            s[blk] = ((r[0] + r[1]) + (r[2] + r[3])) + ((r[4] + r[5]) + (r[6] + r[7]));
        }
        g_esq[k] = s[0] + s[1];
    }
}

// pass1: the r10 GOLDEN K-loop, verbatim (85 us, VGPR 56 + 64 acc = 120 ->
// exactly 2 blocks/CU). HARD-LEARNED CONSTRAINTS (r0/r1 of this session):
//  - arch VGPRs must stay <= 64 (2048/16-wave budget minus acc[4][4]=64).
//  - Deeper prefetch / setprio / ring-mov elimination give ZERO per-wave gain
//    (per-occupancy MFMA ratio 0.65 identical across variants). Occupancy is
//    the only lever that moved pass1. Do not restructure the K-loop.
// Epilogue: the count pass ALSO records the candidate code set {dist < min+TAU}
// (<=CMAX, overflow->flag) so rescue recomputes only those codes instead of
// all 512. Provably identical result: any numpy minimizer k* has
// our_dist(k*) <= our_min + 2*eps < our_min + TAU.
__global__ __launch_bounds__(512) void pass1_fused(const float* __restrict__ z,
                                                   int* __restrict__ out) {
    __shared__ unsigned short Az[2][64 * STRA];   // [0]=hi, [1]=lo ; [px][d]
    __shared__ float s_mn[8][64];
    __shared__ int   s_ixl[8][64];
    __shared__ float s_gm[64];
    __shared__ int   s_gi[64];
    __shared__ int   s_ccn[64];
    __shared__ int   s_cand[64][CMAX];

    const int lane = threadIdx.x & 63;
    const int w    = __builtin_amdgcn_readfirstlane((int)(threadIdx.x >> 6));
    const int l16  = lane & 15, quad = lane >> 4;
    const int n0   = (int)blockIdx.x * 64;        // 64 | 1024 -> same b

    // ---- Prologue: stage A (validated r8). wave w: d-chunk [w*32,w*32+32), lane = px.
    {
        const float* zb = z + ((size_t)(n0 >> 10) << 18) + (n0 & 1023);
        const int px = lane, dc = w;
        #pragma unroll
        for (int half = 0; half < 2; ++half) {
            float x[16];
            #pragma unroll
            for (int j = 0; j < 16; ++j)
                x[j] = zb[(size_t)(dc * 32 + half * 16 + j) * 1024 + px]; // coalesced
            unsigned short h[16], l[16];
            #pragma unroll
            for (int j = 0; j < 16; ++j) {
                h[j] = f2bf(x[j]);
                l[j] = f2bf(x[j] - bf2f(h[j]));
            }
            const int o = px * STRA + dc * 32 + half * 16;
            *(uint4*)&Az[0][o]     = *(uint4*)&h[0];
            *(uint4*)&Az[0][o + 8] = *(uint4*)&h[8];
            *(uint4*)&Az[1][o]     = *(uint4*)&l[0];
            *(uint4*)&Az[1][o + 8] = *(uint4*)&l[8];
        }
    }
    __syncthreads();

    f32x4 acc[4][4];
    #pragma unroll
    for (int i = 0; i < 4; ++i)
        #pragma unroll
        for (int j = 0; j < 4; ++j)
            acc[i][j] = (f32x4){0.f, 0.f, 0.f, 0.f};

    // ---- K-loop: 24 steps, no barriers. seg0: zh*ch, seg1: zh*cl, seg2: zl*ch
    // (chain identical to validated r6/r8). B prefetched one step ahead.
    bf16x8 bcur[4];
    #pragma unroll
    for (int tj = 0; tj < 4; ++tj)
        bcur[tj] = *(const bf16x8*)&g_bph[((size_t)(0 * 32 + w * 4 + tj) * 64 + lane) * 8];

    for (int st = 0; st < 24; ++st) {
        const int seg = st >> 3;
        const int kc  = st & 7;
        const unsigned short* As = Az[(seg == 2) ? 1 : 0];

        bf16x8 bnxt[4];
        if (st < 23) {
            const int sp = st + 1;
            const unsigned short* bp = ((sp >> 3) == 1) ? g_bpl : g_bph;
            const int kcn = sp & 7;
            #pragma unroll
            for (int tj = 0; tj < 4; ++tj)   // 1 KB coalesced per wave, L2-hot
                bnxt[tj] = *(const bf16x8*)&bp[((size_t)(kcn * 32 + w * 4 + tj) * 64 + lane) * 8];
        }

        bf16x8 af[4];
        #pragma unroll
        for (int ti = 0; ti < 4; ++ti)
            af[ti] = *(const bf16x8*)&As[(ti * 16 + l16) * STRA + kc * 32 + quad * 8];

        #pragma unroll
        for (int ti = 0; ti < 4; ++ti)
            #pragma unroll
            for (int tj = 0; tj < 4; ++tj)
                acc[ti][tj] = __builtin_amdgcn_mfma_f32_16x16x32_bf16(
                    af[ti], bcur[tj], acc[ti][tj], 0, 0, 0);

        if (st < 23) {
            #pragma unroll
            for (int tj = 0; tj < 4; ++tj) bcur[tj] = bnxt[tj];
        }
    }

    // ---- Epilogue. C/D: col=lane&15 -> n, row=quad*4+r -> m.
    float esqv[4];
    #pragma unroll
    for (int tj = 0; tj < 4; ++tj) esqv[tj] = g_esq[w * 64 + tj * 16 + l16];
    #pragma unroll
    for (int ti = 0; ti < 4; ++ti)
        #pragma unroll
        for (int tj = 0; tj < 4; ++tj)
            #pragma unroll
            for (int r = 0; r < 4; ++r)
                acc[ti][tj][r] = fmaf(-2.0f, acc[ti][tj][r], esqv[tj]);

    #pragma unroll
    for (int ti = 0; ti < 4; ++ti) {
        #pragma unroll
        for (int r = 0; r < 4; ++r) {
            float bv = __builtin_inff(); int bn = 0x7FFFFFFF;
            #pragma unroll
            for (int tj = 0; tj < 4; ++tj) {
                float s = acc[ti][tj][r];
                int nn = w * 64 + tj * 16 + l16;
                if (s < bv || (s == bv && nn < bn)) { bv = s; bn = nn; }
            }
            #pragma unroll
            for (int off = 1; off <= 8; off <<= 1) {
                float ov = __shfl_xor(bv, off); int on = __shfl_xor(bn, off);
                if (ov < bv || (ov == bv && on < bn)) { bv = ov; bn = on; }
            }
            if (l16 == 0) {
                int m = ti * 16 + quad * 4 + r;
                s_mn[w][m] = bv; s_ixl[w][m] = bn;
            }
        }
    }
    __syncthreads();

    if (threadIdx.x < 64) {
        int m = threadIdx.x;
        float gm = s_mn[0][m]; int gi = s_ixl[0][m];
        #pragma unroll
        for (int q = 1; q < 8; ++q) {
            float v = s_mn[q][m]; int ii = s_ixl[q][m];
            if (v < gm || (v == gm && ii < gi)) { gm = v; gi = ii; }
        }
        s_gm[m] = gm; s_gi[m] = gi; s_ccn[m] = 0;
    }
    __syncthreads();

    // Candidate-append pass (replaces the old count pass; s_ccn ends equal to
    // the old s_cnt: #codes with dist < gm+TAU, which always includes the min).
    // List order is atomic-nondeterministic; rescue argmins over all entries
    // with (dist, code-id) lexicographic order, so order is irrelevant.
    #pragma unroll
    for (int ti = 0; ti < 4; ++ti) {
        #pragma unroll
        for (int r = 0; r < 4; ++r) {
            const int m = ti * 16 + quad * 4 + r;
            const float thr = s_gm[m] + TAU;
            #pragma unroll
            for (int tj = 0; tj < 4; ++tj) {
                if (acc[ti][tj][r] < thr) {
                    int slot = atomicAdd(&s_ccn[m], 1);
                    if (slot < CMAX) s_cand[m][slot] = w * 64 + tj * 16 + l16;
                }
            }
        }
    }
    __syncthreads();

    if (threadIdx.x < 64) {
        int m = threadIdx.x;
        out[n0 + m] = s_gi[m];
        int cnt = s_ccn[m];
        if (cnt >= 2) {
            int pos = atomicAdd(&g_count, 1);
            int ncS = cnt > CMAX ? CMAX : cnt;
            g_list[pos] = (n0 + m) | (ncS << 16) | (cnt > CMAX ? (int)0x80000000 : 0);
            for (int i = 0; i < ncS; ++i) g_cand[pos * CMAX + i] = s_cand[m][i];
        }
    }
}

// Rescue: numpy-bit-exact (validated r4/r5/r8). One wave per flagged pixel.
// Only the recorded candidate codes are recomputed (lane i -> cand[i]);
// per-code math (zsq shuffle pattern, a8a/a8b double-FMA split, final
// fp32 rounding chain) is VERBATIM the validated full-scan body, so each
// candidate's dist is bit-identical to what the full scan would produce.
// The TAU guarantee puts every possible numpy argmin in the candidate set,
// so the restricted argmin equals the full argmin. Overflow (>CMAX) pixels
// take the original full-512 path, preserved below.
__global__ __launch_bounds__(256) void rescue_kernel(const float* __restrict__ z,
                                                     int* __restrict__ out) {
    const int lane = threadIdx.x & 63;
    const int wg   = (int)blockIdx.x * 4 + (int)(threadIdx.x >> 6);
    const int nw   = (int)gridDim.x * 4;
    const int count = g_count;

    for (int it = wg; it < count; it += nw) {
        const int entry = g_list[it];
        const int n  = entry & 0xFFFF;
        const int nc = (entry >> 16) & 0x1F;
        const bool full = entry < 0;               // overflow -> full scan
        const float* zp = z + ((size_t)(n >> 10) << 18) + (n & 1023);

        float zf[4], xsq[4];
        #pragma unroll
        for (int q = 0; q < 4; ++q) zf[q] = zp[(size_t)((q << 6) + lane) << 10];
        #pragma unroll
        for (int q = 0; q < 4; ++q) xsq[q] = zf[q] * zf[q];

        // numpy pairwise zsq via shuffles (bit-exact, validated r5)
        const int j = lane & 7;
        float r0 = __shfl(xsq[0], j);
        #pragma unroll
        for (int t = 1; t < 8; ++t) r0 += __shfl(xsq[0], 8 * t + j);
        #pragma unroll
        for (int t = 0; t < 8; ++t) r0 += __shfl(xsq[1], 8 * t + j);
        float r1 = __shfl(xsq[2], j);
        #pragma unroll
        for (int t = 1; t < 8; ++t) r1 += __shfl(xsq[2], 8 * t + j);
        #pragma unroll
        for (int t = 0; t < 8; ++t) r1 += __shfl(xsq[3], 8 * t + j);
        r0 = r0 + __shfl_xor(r0, 1); r0 = r0 + __shfl_xor(r0, 2); r0 = r0 + __shfl_xor(r0, 4);
        r1 = r1 + __shfl_xor(r1, 1); r1 = r1 + __shfl_xor(r1, 2); r1 = r1 + __shfl_xor(r1, 4);
        const float zsq = r0 + r1;

        float best = __builtin_inff(); int bi = 0x7FFFFFFF;

        if (!full) {
            // Candidate path: lane i handles candidate i (lanes >= nc duplicate
            // candidate 0 -- idempotent under (dist, idx) min-reduce).
            const int kk = g_cand[it * CMAX + (lane < nc ? lane : 0)];
            double a8a = 0.0, a8b = 0.0;
            for (int dq = 0; dq < D_DIM / 4; ++dq) {
                const int d0 = dq * 4;
                double zd0 = (double)__shfl(zf[(d0    ) >> 6], (d0    ) & 63);
                double zd1 = (double)__shfl(zf[(d0 + 1) >> 6], (d0 + 1) & 63);
                double zd2 = (double)__shfl(zf[(d0 + 2) >> 6], (d0 + 2) & 63);
                double zd3 = (double)__shfl(zf[(d0 + 3) >> 6], (d0 + 3) & 63);
                float4 c4 = g_cbF4[dq * K_CODES + kk];
                a8a = fma((double)c4.x, zd0, a8a);
                a8a = fma((double)c4.y, zd1, a8a);
                a8b = fma((double)c4.z, zd2, a8b);
                a8b = fma((double)c4.w, zd3, a8b);
            }
            float c32 = (float)(a8a + a8b);
            float t = zsq - 2.0f * c32;
            best = t + g_esq[kk];
            bi = kk;
        } else {
            // Original full-512 path, verbatim (overflow fallback).
            double a8a[8], a8b[8];
            #pragma unroll
            for (int jj = 0; jj < 8; ++jj) { a8a[jj] = 0.0; a8b[jj] = 0.0; }
            for (int dq = 0; dq < D_DIM / 4; ++dq) {
                const int d0 = dq * 4;
                double zd0 = (double)__shfl(zf[(d0    ) >> 6], (d0    ) & 63);
                double zd1 = (double)__shfl(zf[(d0 + 1) >> 6], (d0 + 1) & 63);
                double zd2 = (double)__shfl(zf[(d0 + 2) >> 6], (d0 + 2) & 63);
                double zd3 = (double)__shfl(zf[(d0 + 3) >> 6], (d0 + 3) & 63);
                #pragma unroll
                for (int jj = 0; jj < 8; ++jj) {
                    float4 c4 = g_cbF4[dq * K_CODES + lane + (jj << 6)];
                    a8a[jj] = fma((double)c4.x, zd0, a8a[jj]);
                    a8a[jj] = fma((double)c4.y, zd1, a8a[jj]);
                    a8b[jj] = fma((double)c4.z, zd2, a8b[jj]);
                    a8b[jj] = fma((double)c4.w, zd3, a8b[jj]);
                }
            }
            #pragma unroll
            for (int jj = 0; jj < 8; ++jj) {
                int kk = lane + (jj << 6);
                float c32 = (float)(a8a[jj] + a8b[jj]);
                float t = zsq - 2.0f * c32;
                float dist = t + g_esq[kk];
                if (dist < best || (dist == best && kk < bi)) { best = dist; bi = kk; }
            }
        }

        #pragma unroll
        for (int off = 32; off; off >>= 1) {
            float ob = __shfl_xor(best, off);
            int   oi = __shfl_xor(bi, off);
            if (ob < best || (ob == best && oi < bi)) { best = ob; bi = oi; }
        }
        if (lane == 0) out[n] = bi;
    }
}

extern "C" void kernel_launch(void* const* d_in, const int* in_sizes, int n_in,
                              void* d_out, int out_size, void* d_ws, size_t ws_size,
                              hipStream_t stream) {
    const float* z_e_x    = (const float*)d_in[0];   // [64, 256, 32, 32] fp32
    const float* codebook = (const float*)d_in[1];   // [512, 256] fp32
    int* out = (int*)d_out;                          // [65536] int32

    prep_cb<<<dim3(64), dim3(256), 0, stream>>>(codebook);
    pass1_fused<<<dim3(1024), dim3(512), 0, stream>>>(z_e_x, out);
    rescue_kernel<<<dim3(512), dim3(256), 0, stream>>>(z_e_x, out);
}